// Round 1
// baseline (1259.003 us; speedup 1.0000x reference)
//
#include <hip/hip_runtime.h>
#include <math.h>

#define DMODEL 384
#define DIN 768
#define NST 16
#define DTR 48
#define BSZ 8
#define LSEQ 1024
#define NROWS (BSZ*LSEQ)      // 8192
#define XPO_W (DTR + 2*NST)   // 80

// ---------------- LayerNorm: one wave per row ----------------
__global__ __launch_bounds__(64) void ln_kernel(const float* __restrict__ x,
    const float* __restrict__ g, const float* __restrict__ b, float* __restrict__ xn) {
  int row = blockIdx.x;
  int lane = threadIdx.x;
  const float* xr = x + (size_t)row * DMODEL;
  float v[6];
  float s = 0.f, ss = 0.f;
#pragma unroll
  for (int i = 0; i < 6; ++i) { v[i] = xr[lane + i*64]; s += v[i]; ss += v[i]*v[i]; }
#pragma unroll
  for (int off = 32; off; off >>= 1) { s += __shfl_xor(s, off); ss += __shfl_xor(ss, off); }
  float mu = s * (1.f / DMODEL);
  float var = ss * (1.f / DMODEL) - mu * mu;
  float inv = rsqrtf(var + 1e-5f);
  float* xo = xn + (size_t)row * DMODEL;
#pragma unroll
  for (int i = 0; i < 6; ++i) {
    int c = lane + i*64;
    xo[c] = (v[i] - mu) * inv * g[c] + b[c];
  }
}

// ---------------- Generic tiled fp32 GEMM: C[M,N] = A[M,K](lda) * B[N,K]^T ----------------
// EPI: 0 none, 2 bias+softplus, 3 residual add
template<int EPI>
__global__ __launch_bounds__(256) void gemm_bt(
    const float* __restrict__ A, int lda,
    const float* __restrict__ B,   // [N,K] row-major
    float* __restrict__ C,
    const float* __restrict__ bias,
    const float* __restrict__ res,
    int M, int N, int K) {
  __shared__ float As[16][68];
  __shared__ float Bs[16][68];
  int tid = threadIdx.x;
  int tx = tid & 15, ty = tid >> 4;
  int m0 = blockIdx.y * 64, n0 = blockIdx.x * 64;
  float acc[4][4] = {};
  for (int kt = 0; kt < K; kt += 16) {
#pragma unroll
    for (int i = 0; i < 4; ++i) {
      int e = tid + i*256;
      int mm = e >> 4, kk = e & 15;
      int gm = m0 + mm, gk = kt + kk;
      As[kk][mm] = (gm < M && gk < K) ? A[(size_t)gm*lda + gk] : 0.f;
      int gn = n0 + mm;
      Bs[kk][mm] = (gn < N && gk < K) ? B[(size_t)gn*K + gk] : 0.f;
    }
    __syncthreads();
#pragma unroll
    for (int kk = 0; kk < 16; ++kk) {
      float4 a4 = *reinterpret_cast<const float4*>(&As[kk][ty*4]);
      float4 b4 = *reinterpret_cast<const float4*>(&Bs[kk][tx*4]);
      float av[4] = {a4.x, a4.y, a4.z, a4.w};
      float bv[4] = {b4.x, b4.y, b4.z, b4.w};
#pragma unroll
      for (int i = 0; i < 4; ++i)
#pragma unroll
        for (int j = 0; j < 4; ++j)
          acc[i][j] = fmaf(av[i], bv[j], acc[i][j]);
    }
    __syncthreads();
  }
#pragma unroll
  for (int i = 0; i < 4; ++i) {
    int m = m0 + ty*4 + i;
    if (m >= M) continue;
#pragma unroll
    for (int j = 0; j < 4; ++j) {
      int n = n0 + tx*4 + j;
      if (n >= N) continue;
      float v = acc[i][j];
      if (EPI == 2) { v += bias[n]; v = (v > 20.f) ? v : log1pf(expf(v)); }
      if (EPI == 3) { v += res[(size_t)m*N + n]; }
      C[(size_t)m*N + n] = v;
    }
  }
}

// ---------------- causal depthwise conv (width 4) + SiLU ----------------
__global__ __launch_bounds__(256) void conv_silu_kernel(
    const float* __restrict__ xz, const float* __restrict__ w,
    const float* __restrict__ cb, float* __restrict__ u) {
  int idx = blockIdx.x * 256 + threadIdx.x;
  if (idx >= NROWS * DIN) return;
  int d = idx % DIN;
  int r = idx / DIN;          // b*L + l
  int l = r & (LSEQ - 1);
  float acc = cb[d];
#pragma unroll
  for (int j = 0; j < 4; ++j) {
    int li = l - 3 + j;
    if (li >= 0)
      acc = fmaf(xz[(size_t)(r - l + li) * (2*DIN) + d], w[d*4 + j], acc);
  }
  u[idx] = acc / (1.f + expf(-acc));   // silu
}

// ---------------- selective scan: 16 n-lanes per d, shuffle-reduce y ----------------
__global__ __launch_bounds__(256) void scan_kernel(
    const float* __restrict__ delta, const float* __restrict__ u,
    const float* __restrict__ xpo, const float* __restrict__ xz,
    const float* __restrict__ A_log, const float* __restrict__ Dp,
    float* __restrict__ y2) {
  int n = threadIdx.x & 15;
  int dloc = threadIdx.x >> 4;
  int d = blockIdx.x * 16 + dloc;
  int b = blockIdx.y;
  float A = -expf(A_log[d*NST + n]);
  float Dd = Dp[d];
  const float* dp = delta + (size_t)b*LSEQ*DIN + d;
  const float* up = u     + (size_t)b*LSEQ*DIN + d;
  const float* bp = xpo   + (size_t)b*LSEQ*XPO_W + DTR + n;
  const float* cp = bp + NST;
  const float* zp = xz    + (size_t)b*LSEQ*(2*DIN) + DIN + d;
  float*       yp = y2    + (size_t)b*LSEQ*DIN + d;
  float h = 0.f;
#pragma unroll 4
  for (int l = 0; l < LSEQ; ++l) {
    float dv = dp[(size_t)l*DIN];
    float uv = up[(size_t)l*DIN];
    float bv = bp[(size_t)l*XPO_W];
    float cv = cp[(size_t)l*XPO_W];
    float dA = expf(dv * A);
    h = fmaf(dA, h, dv * uv * bv);
    float p = h * cv;
    p += __shfl_xor(p, 8);
    p += __shfl_xor(p, 4);
    p += __shfl_xor(p, 2);
    p += __shfl_xor(p, 1);
    if (n == 0) {
      float z = zp[(size_t)l*(2*DIN)];
      float sz = z / (1.f + expf(-z));
      yp[(size_t)l*DIN] = (p + uv * Dd) * sz;
    }
  }
}

extern "C" void kernel_launch(void* const* d_in, const int* in_sizes, int n_in,
                              void* d_out, int out_size, void* d_ws, size_t ws_size,
                              hipStream_t stream) {
  const float* x          = (const float*)d_in[0];
  const float* ln_g       = (const float*)d_in[1];
  const float* ln_b       = (const float*)d_in[2];
  const float* in_proj_w  = (const float*)d_in[3];   // (1536,384)
  const float* conv_w     = (const float*)d_in[4];   // (768,1,4)
  const float* conv_b     = (const float*)d_in[5];
  const float* x_proj_w   = (const float*)d_in[6];   // (80,768)
  const float* dt_proj_w  = (const float*)d_in[7];   // (768,48)
  const float* dt_proj_b  = (const float*)d_in[8];
  const float* A_log      = (const float*)d_in[9];   // (768,16)
  const float* D_param    = (const float*)d_in[10];
  const float* out_proj_w = (const float*)d_in[11];  // (384,768)

  float* ws    = (float*)d_ws;
  float* xn    = ws;                                  // 8192*384
  float* xz    = xn    + (size_t)NROWS*DMODEL;        // 8192*1536
  float* u     = xz    + (size_t)NROWS*2*DIN;         // 8192*768
  float* xpo   = u     + (size_t)NROWS*DIN;           // 8192*80
  float* delta = xpo   + (size_t)NROWS*XPO_W;         // 8192*768
  float* y2    = delta + (size_t)NROWS*DIN;           // 8192*768

  // 1. LayerNorm
  ln_kernel<<<NROWS, 64, 0, stream>>>(x, ln_g, ln_b, xn);

  // 2. in_proj: xz = xn @ in_proj_w^T   (M=8192,N=1536,K=384)
  {
    dim3 g(2*DIN/64, NROWS/64);
    gemm_bt<0><<<g, 256, 0, stream>>>(xn, DMODEL, in_proj_w, xz, nullptr, nullptr,
                                      NROWS, 2*DIN, DMODEL);
  }

  // 3. conv + silu -> u
  conv_silu_kernel<<<(NROWS*DIN + 255)/256, 256, 0, stream>>>(xz, conv_w, conv_b, u);

  // 4. x_proj: xpo = u @ x_proj_w^T    (M=8192,N=80,K=768)
  {
    dim3 g((XPO_W + 63)/64, NROWS/64);
    gemm_bt<0><<<g, 256, 0, stream>>>(u, DIN, x_proj_w, xpo, nullptr, nullptr,
                                      NROWS, XPO_W, DIN);
  }

  // 5. dt_proj + bias + softplus -> delta   (M=8192,N=768,K=48, lda=80)
  {
    dim3 g(DIN/64, NROWS/64);
    gemm_bt<2><<<g, 256, 0, stream>>>(xpo, XPO_W, dt_proj_w, delta, dt_proj_b, nullptr,
                                      NROWS, DIN, DTR);
  }

  // 6. selective scan + gating epilogue -> y2
  {
    dim3 g(DIN/16, BSZ);
    scan_kernel<<<g, 256, 0, stream>>>(delta, u, xpo, xz, A_log, D_param, y2);
  }

  // 7. out_proj + residual -> d_out   (M=8192,N=384,K=768)
  {
    dim3 g(DMODEL/64, NROWS/64);
    gemm_bt<3><<<g, 256, 0, stream>>>(y2, DIN, out_proj_w, (float*)d_out, nullptr, x,
                                      NROWS, DMODEL, DIN);
  }
}

// Round 2
// 531.818 us; speedup vs baseline: 2.3674x; 2.3674x over previous
//
#include <hip/hip_runtime.h>
#include <math.h>

#define DMODEL 384
#define DIN 768
#define NST 16
#define DTR 48
#define BSZ 8
#define LSEQ 1024
#define NROWS (BSZ*LSEQ)      // 8192
#define XPO_W (DTR + 2*NST)   // 80
#define CL 64                 // chunk length for scan
#define NC (LSEQ/CL)          // 16 chunks

// ---------------- LayerNorm: one wave per row ----------------
__global__ __launch_bounds__(64) void ln_kernel(const float* __restrict__ x,
    const float* __restrict__ g, const float* __restrict__ b, float* __restrict__ xn) {
  int row = blockIdx.x;
  int lane = threadIdx.x;
  const float* xr = x + (size_t)row * DMODEL;
  float v[6];
  float s = 0.f, ss = 0.f;
#pragma unroll
  for (int i = 0; i < 6; ++i) { v[i] = xr[lane + i*64]; s += v[i]; ss += v[i]*v[i]; }
#pragma unroll
  for (int off = 32; off; off >>= 1) { s += __shfl_xor(s, off); ss += __shfl_xor(ss, off); }
  float mu = s * (1.f / DMODEL);
  float var = ss * (1.f / DMODEL) - mu * mu;
  float inv = rsqrtf(var + 1e-5f);
  float* xo = xn + (size_t)row * DMODEL;
#pragma unroll
  for (int i = 0; i < 6; ++i) {
    int c = lane + i*64;
    xo[c] = (v[i] - mu) * inv * g[c] + b[c];
  }
}

// ---------------- Generic tiled fp32 GEMM: C[M,N] = A[M,K](lda) * B[N,K]^T ----------------
// EPI: 0 none, 2 bias+softplus, 3 residual add
template<int EPI>
__global__ __launch_bounds__(256) void gemm_bt(
    const float* __restrict__ A, int lda,
    const float* __restrict__ B,   // [N,K] row-major
    float* __restrict__ C,
    const float* __restrict__ bias,
    const float* __restrict__ res,
    int M, int N, int K) {
  __shared__ float As[16][68];
  __shared__ float Bs[16][68];
  int tid = threadIdx.x;
  int tx = tid & 15, ty = tid >> 4;
  int m0 = blockIdx.y * 64, n0 = blockIdx.x * 64;
  float acc[4][4] = {};
  for (int kt = 0; kt < K; kt += 16) {
#pragma unroll
    for (int i = 0; i < 4; ++i) {
      int e = tid + i*256;
      int mm = e >> 4, kk = e & 15;
      int gm = m0 + mm, gk = kt + kk;
      As[kk][mm] = (gm < M && gk < K) ? A[(size_t)gm*lda + gk] : 0.f;
      int gn = n0 + mm;
      Bs[kk][mm] = (gn < N && gk < K) ? B[(size_t)gn*K + gk] : 0.f;
    }
    __syncthreads();
#pragma unroll
    for (int kk = 0; kk < 16; ++kk) {
      float4 a4 = *reinterpret_cast<const float4*>(&As[kk][ty*4]);
      float4 b4 = *reinterpret_cast<const float4*>(&Bs[kk][tx*4]);
      float av[4] = {a4.x, a4.y, a4.z, a4.w};
      float bv[4] = {b4.x, b4.y, b4.z, b4.w};
#pragma unroll
      for (int i = 0; i < 4; ++i)
#pragma unroll
        for (int j = 0; j < 4; ++j)
          acc[i][j] = fmaf(av[i], bv[j], acc[i][j]);
    }
    __syncthreads();
  }
#pragma unroll
  for (int i = 0; i < 4; ++i) {
    int m = m0 + ty*4 + i;
    if (m >= M) continue;
#pragma unroll
    for (int j = 0; j < 4; ++j) {
      int n = n0 + tx*4 + j;
      if (n >= N) continue;
      float v = acc[i][j];
      if (EPI == 2) { v += bias[n]; v = (v > 20.f) ? v : log1pf(expf(v)); }
      if (EPI == 3) { v += res[(size_t)m*N + n]; }
      C[(size_t)m*N + n] = v;
    }
  }
}

// ---------------- causal depthwise conv (width 4) + SiLU ----------------
__global__ __launch_bounds__(256) void conv_silu_kernel(
    const float* __restrict__ xz, const float* __restrict__ w,
    const float* __restrict__ cb, float* __restrict__ u) {
  int idx = blockIdx.x * 256 + threadIdx.x;
  if (idx >= NROWS * DIN) return;
  int d = idx % DIN;
  int r = idx / DIN;          // b*L + l
  int l = r & (LSEQ - 1);
  float acc = cb[d];
#pragma unroll
  for (int j = 0; j < 4; ++j) {
    int li = l - 3 + j;
    if (li >= 0)
      acc = fmaf(xz[(size_t)(r - l + li) * (2*DIN) + d], w[d*4 + j], acc);
  }
  u[idx] = acc / (1.f + expf(-acc));   // silu
}

// ---------------- chunked selective scan ----------------
// pass1: per (b,chunk,d) lane holds all 16 n-states; emit chunk carry (prod a, h_end)
__global__ __launch_bounds__(256) void scan_pass1(
    const float* __restrict__ delta, const float* __restrict__ u,
    const float* __restrict__ xpo, const float* __restrict__ A_log,
    float* __restrict__ carryA, float* __restrict__ carryH) {
  int d = blockIdx.x * 256 + threadIdx.x;   // grid.x = DIN/256
  int c = blockIdx.y, b = blockIdx.z;
  float A[16];
  {
    const float4* al = reinterpret_cast<const float4*>(A_log + (size_t)d * NST);
#pragma unroll
    for (int i = 0; i < 4; ++i) {
      float4 t = al[i];
      A[4*i+0] = -__expf(t.x); A[4*i+1] = -__expf(t.y);
      A[4*i+2] = -__expf(t.z); A[4*i+3] = -__expf(t.w);
    }
  }
  float h[16], ap[16];
#pragma unroll
  for (int n = 0; n < 16; ++n) { h[n] = 0.f; ap[n] = 1.f; }
  const float* dp = delta + ((size_t)b*LSEQ + c*CL) * DIN + d;
  const float* up = u     + ((size_t)b*LSEQ + c*CL) * DIN + d;
  const float* bp = xpo   + ((size_t)b*LSEQ + c*CL) * XPO_W + DTR;
  for (int l = 0; l < CL; ++l) {
    float dv = dp[(size_t)l*DIN];
    float uv = up[(size_t)l*DIN];
    float du = dv * uv;
    float Bv[16];
    {
      const float4* b4 = reinterpret_cast<const float4*>(bp + (size_t)l*XPO_W);
#pragma unroll
      for (int i = 0; i < 4; ++i) {
        float4 t = b4[i];
        Bv[4*i+0] = t.x; Bv[4*i+1] = t.y; Bv[4*i+2] = t.z; Bv[4*i+3] = t.w;
      }
    }
#pragma unroll
    for (int n = 0; n < 16; ++n) {
      float a = __expf(dv * A[n]);
      ap[n] *= a;
      h[n] = fmaf(a, h[n], du * Bv[n]);
    }
  }
  size_t ci = (((size_t)b*NC + c) * DIN + d) * NST;
  float4* ca = reinterpret_cast<float4*>(carryA + ci);
  float4* ch = reinterpret_cast<float4*>(carryH + ci);
#pragma unroll
  for (int i = 0; i < 4; ++i) {
    ca[i] = make_float4(ap[4*i], ap[4*i+1], ap[4*i+2], ap[4*i+3]);
    ch[i] = make_float4(h[4*i],  h[4*i+1],  h[4*i+2],  h[4*i+3]);
  }
}

// mid: sequential scan over NC chunk carries, in-place: carryH[c] becomes h_in of chunk c
__global__ __launch_bounds__(256) void scan_mid(
    const float* __restrict__ carryA, float* __restrict__ carryH) {
  int idx = blockIdx.x * 256 + threadIdx.x;   // [0, BSZ*DIN*NST)
  int b = idx / (DIN*NST);
  int rem = idx - b * DIN*NST;
  float h = 0.f;
#pragma unroll
  for (int c = 0; c < NC; ++c) {
    size_t i = ((size_t)b*NC + c) * (DIN*NST) + rem;
    float a = carryA[i];
    float e = carryH[i];
    carryH[i] = h;
    h = fmaf(a, h, e);
  }
}

// pass2: recompute in-chunk scan seeded with h_in; fuse y = (h·C + u·D)·silu(z)
__global__ __launch_bounds__(256) void scan_pass2(
    const float* __restrict__ delta, const float* __restrict__ u,
    const float* __restrict__ xpo, const float* __restrict__ xz,
    const float* __restrict__ A_log, const float* __restrict__ Dp,
    const float* __restrict__ carryH, float* __restrict__ y2) {
  int d = blockIdx.x * 256 + threadIdx.x;
  int c = blockIdx.y, b = blockIdx.z;
  float A[16];
  {
    const float4* al = reinterpret_cast<const float4*>(A_log + (size_t)d * NST);
#pragma unroll
    for (int i = 0; i < 4; ++i) {
      float4 t = al[i];
      A[4*i+0] = -__expf(t.x); A[4*i+1] = -__expf(t.y);
      A[4*i+2] = -__expf(t.z); A[4*i+3] = -__expf(t.w);
    }
  }
  float h[16];
  size_t ci = (((size_t)b*NC + c) * DIN + d) * NST;
  {
    const float4* ch = reinterpret_cast<const float4*>(carryH + ci);
#pragma unroll
    for (int i = 0; i < 4; ++i) {
      float4 t = ch[i];
      h[4*i+0] = t.x; h[4*i+1] = t.y; h[4*i+2] = t.z; h[4*i+3] = t.w;
    }
  }
  float Dd = Dp[d];
  const float* dp = delta + ((size_t)b*LSEQ + c*CL) * DIN + d;
  const float* up = u     + ((size_t)b*LSEQ + c*CL) * DIN + d;
  const float* bp = xpo   + ((size_t)b*LSEQ + c*CL) * XPO_W + DTR;
  const float* zp = xz    + ((size_t)b*LSEQ + c*CL) * (2*DIN) + DIN + d;
  float*       yp = y2    + ((size_t)b*LSEQ + c*CL) * DIN + d;
  for (int l = 0; l < CL; ++l) {
    float dv = dp[(size_t)l*DIN];
    float uv = up[(size_t)l*DIN];
    float du = dv * uv;
    float Bv[16], Cv[16];
    {
      const float4* b4 = reinterpret_cast<const float4*>(bp + (size_t)l*XPO_W);
#pragma unroll
      for (int i = 0; i < 4; ++i) {
        float4 t = b4[i];
        Bv[4*i+0] = t.x; Bv[4*i+1] = t.y; Bv[4*i+2] = t.z; Bv[4*i+3] = t.w;
        float4 tc = b4[i+4];
        Cv[4*i+0] = tc.x; Cv[4*i+1] = tc.y; Cv[4*i+2] = tc.z; Cv[4*i+3] = tc.w;
      }
    }
    float p = 0.f;
#pragma unroll
    for (int n = 0; n < 16; ++n) {
      float a = __expf(dv * A[n]);
      h[n] = fmaf(a, h[n], du * Bv[n]);
      p = fmaf(h[n], Cv[n], p);
    }
    float z = zp[(size_t)l*(2*DIN)];
    float sz = z / (1.f + expf(-z));
    yp[(size_t)l*DIN] = fmaf(uv, Dd, p) * sz;
  }
}

extern "C" void kernel_launch(void* const* d_in, const int* in_sizes, int n_in,
                              void* d_out, int out_size, void* d_ws, size_t ws_size,
                              hipStream_t stream) {
  const float* x          = (const float*)d_in[0];
  const float* ln_g       = (const float*)d_in[1];
  const float* ln_b       = (const float*)d_in[2];
  const float* in_proj_w  = (const float*)d_in[3];   // (1536,384)
  const float* conv_w     = (const float*)d_in[4];   // (768,1,4)
  const float* conv_b     = (const float*)d_in[5];
  const float* x_proj_w   = (const float*)d_in[6];   // (80,768)
  const float* dt_proj_w  = (const float*)d_in[7];   // (768,48)
  const float* dt_proj_b  = (const float*)d_in[8];
  const float* A_log      = (const float*)d_in[9];   // (768,16)
  const float* D_param    = (const float*)d_in[10];
  const float* out_proj_w = (const float*)d_in[11];  // (384,768)

  float* ws    = (float*)d_ws;
  float* xn    = ws;                                  // 8192*384 (reused as carries later)
  float* xz    = xn    + (size_t)NROWS*DMODEL;        // 8192*1536
  float* u     = xz    + (size_t)NROWS*2*DIN;         // 8192*768
  float* xpo   = u     + (size_t)NROWS*DIN;           // 8192*80
  float* delta = xpo   + (size_t)NROWS*XPO_W;         // 8192*768
  float* y2    = delta + (size_t)NROWS*DIN;           // 8192*768

  // scan carries reuse xn region (dead after in_proj): 2 x BSZ*NC*DIN*NST = 2 x 1.57M floats
  float* carryA = xn;
  float* carryH = xn + (size_t)BSZ*NC*DIN*NST;

  // 1. LayerNorm
  ln_kernel<<<NROWS, 64, 0, stream>>>(x, ln_g, ln_b, xn);

  // 2. in_proj: xz = xn @ in_proj_w^T   (M=8192,N=1536,K=384)
  {
    dim3 g(2*DIN/64, NROWS/64);
    gemm_bt<0><<<g, 256, 0, stream>>>(xn, DMODEL, in_proj_w, xz, nullptr, nullptr,
                                      NROWS, 2*DIN, DMODEL);
  }

  // 3. conv + silu -> u
  conv_silu_kernel<<<(NROWS*DIN + 255)/256, 256, 0, stream>>>(xz, conv_w, conv_b, u);

  // 4. x_proj: xpo = u @ x_proj_w^T    (M=8192,N=80,K=768)
  {
    dim3 g((XPO_W + 63)/64, NROWS/64);
    gemm_bt<0><<<g, 256, 0, stream>>>(u, DIN, x_proj_w, xpo, nullptr, nullptr,
                                      NROWS, XPO_W, DIN);
  }

  // 5. dt_proj + bias + softplus -> delta   (M=8192,N=768,K=48, lda=80)
  {
    dim3 g(DIN/64, NROWS/64);
    gemm_bt<2><<<g, 256, 0, stream>>>(xpo, XPO_W, dt_proj_w, delta, dt_proj_b, nullptr,
                                      NROWS, DIN, DTR);
  }

  // 6. chunked selective scan + gating epilogue -> y2
  {
    dim3 g1(DIN/256, NC, BSZ);
    scan_pass1<<<g1, 256, 0, stream>>>(delta, u, xpo, A_log, carryA, carryH);
    scan_mid<<<(BSZ*DIN*NST)/256, 256, 0, stream>>>(carryA, carryH);
    scan_pass2<<<g1, 256, 0, stream>>>(delta, u, xpo, xz, A_log, D_param, carryH, y2);
  }

  // 7. out_proj + residual -> d_out   (M=8192,N=384,K=768)
  {
    dim3 g(DMODEL/64, NROWS/64);
    gemm_bt<3><<<g, 256, 0, stream>>>(y2, DIN, out_proj_w, (float*)d_out, nullptr, x,
                                      NROWS, DMODEL, DIN);
  }
}

// Round 3
// 309.578 us; speedup vs baseline: 4.0668x; 1.7179x over previous
//
#include <hip/hip_runtime.h>
#include <math.h>

#define DMODEL 384
#define DIN 768
#define NST 16
#define DTR 48
#define BSZ 8
#define LSEQ 1024
#define NROWS (BSZ*LSEQ)      // 8192
#define XPO_W (DTR + 2*NST)   // 80
#define CL 64                 // chunk length for scan
#define NC (LSEQ/CL)          // 16 chunks

typedef __attribute__((ext_vector_type(8))) short bf16x8;
typedef __attribute__((ext_vector_type(4))) float f32x4;

__device__ __forceinline__ unsigned short f2bf(float x) {
  unsigned int u = __float_as_uint(x);
  unsigned int r = u + 0x7fffu + ((u >> 16) & 1u);
  return (unsigned short)(r >> 16);
}
__device__ __forceinline__ float bf2f(unsigned short h) {
  return __uint_as_float(((unsigned int)h) << 16);
}

__device__ __forceinline__ void gll16(const void* g, void* l) {
  __builtin_amdgcn_global_load_lds(
      (const __attribute__((address_space(1))) void*)g,
      (__attribute__((address_space(3))) void*)l, 16, 0, 0);
}

// ---------------- LayerNorm: one wave per row, emits hi/lo bf16 split ----------------
__global__ __launch_bounds__(64) void ln_kernel(const float* __restrict__ x,
    const float* __restrict__ g, const float* __restrict__ b,
    unsigned short* __restrict__ xh, unsigned short* __restrict__ xl) {
  int row = blockIdx.x;
  int lane = threadIdx.x;
  const float* xr = x + (size_t)row * DMODEL;
  float v[6];
  float s = 0.f, ss = 0.f;
#pragma unroll
  for (int i = 0; i < 6; ++i) { v[i] = xr[lane + i*64]; s += v[i]; ss += v[i]*v[i]; }
#pragma unroll
  for (int off = 32; off; off >>= 1) { s += __shfl_xor(s, off); ss += __shfl_xor(ss, off); }
  float mu = s * (1.f / DMODEL);
  float var = ss * (1.f / DMODEL) - mu * mu;
  float inv = rsqrtf(var + 1e-5f);
#pragma unroll
  for (int i = 0; i < 6; ++i) {
    int c = lane + i*64;
    float o = (v[i] - mu) * inv * g[c] + b[c];
    unsigned short hv = f2bf(o);
    xh[(size_t)row*DMODEL + c] = hv;
    xl[(size_t)row*DMODEL + c] = f2bf(o - bf2f(hv));
  }
}

// ---------------- split+pad fp32 -> bf16 hi/lo ----------------
__global__ __launch_bounds__(256) void split_pad(
    const float* __restrict__ src, int ldsrc, int R, int C,
    unsigned short* __restrict__ dh, unsigned short* __restrict__ dl, int Cpad) {
  int i = blockIdx.x * 256 + threadIdx.x;
  int r = i / Cpad, c = i - r * Cpad;
  float v = (r < R && c < C) ? src[(size_t)r*ldsrc + c] : 0.f;
  unsigned short hv = f2bf(v);
  dh[i] = hv;
  dl[i] = f2bf(v - bf2f(hv));
}

// ---------------- MFMA split-bf16 GEMM: C[M,Npad] = A[M,K] * B[Npad,K]^T ----------------
// 128x128 tile, BK=32, 4 waves (2x2) each 64x64 via 16x16x32 bf16 MFMA.
// EPI: 0 plain store, 2 bias+softplus, 3 residual add, 4 x_proj (xpo fp32 + dlow hi/lo pad)
template<int EPI>
__global__ __launch_bounds__(256, 2) void gemm_mfma(
    const unsigned short* __restrict__ Ah, const unsigned short* __restrict__ Al, int lda,
    const unsigned short* __restrict__ Bh, const unsigned short* __restrict__ Bl, int ldb,
    float* __restrict__ C, int ldc,
    const float* __restrict__ bias, const float* __restrict__ res,
    unsigned short* __restrict__ oh, unsigned short* __restrict__ ol,
    int K) {
  // LDS layout per array: [kgroup(4)][row(128)][8 bf16] -> 16B cells, 8KB each
  __shared__ unsigned short As_h[512*8], As_l[512*8], Bs_h[512*8], Bs_l[512*8];
  int tid = threadIdx.x;
  int lane = tid & 63, wid = tid >> 6;
  int wm = wid >> 1, wn = wid & 1;
  int m0 = blockIdx.y * 128, n0 = blockIdx.x * 128;
  f32x4 acc[4][4];
#pragma unroll
  for (int i = 0; i < 4; ++i)
#pragma unroll
    for (int j = 0; j < 4; ++j) acc[i][j] = (f32x4){0.f, 0.f, 0.f, 0.f};

  int kgl = lane >> 4, rl = lane & 15;

  for (int kt = 0; kt < K; kt += 32) {
    // stage 4 arrays, each wave fills 128 cells (2 issues of 64 lanes x 16B)
#pragma unroll
    for (int j = 0; j < 2; ++j) {
      int c = wid*128 + j*64 + lane;
      int r = c & 127, kg = c >> 7;
      size_t ga = (size_t)(m0 + r) * lda + kt + kg*8;
      size_t gb = (size_t)(n0 + r) * ldb + kt + kg*8;
      int lo = (wid*128 + j*64) * 8;
      gll16(Ah + ga, &As_h[lo]);
      gll16(Al + ga, &As_l[lo]);
      gll16(Bh + gb, &Bs_h[lo]);
      gll16(Bl + gb, &Bs_l[lo]);
    }
    __syncthreads();
    bf16x8 ah[4], al[4], bh[4], bl[4];
#pragma unroll
    for (int mi = 0; mi < 4; ++mi) {
      int cell = kgl*128 + wm*64 + mi*16 + rl;
      ah[mi] = *reinterpret_cast<const bf16x8*>(&As_h[cell*8]);
      al[mi] = *reinterpret_cast<const bf16x8*>(&As_l[cell*8]);
    }
#pragma unroll
    for (int ni = 0; ni < 4; ++ni) {
      int cell = kgl*128 + wn*64 + ni*16 + rl;
      bh[ni] = *reinterpret_cast<const bf16x8*>(&Bs_h[cell*8]);
      bl[ni] = *reinterpret_cast<const bf16x8*>(&Bs_l[cell*8]);
    }
#pragma unroll
    for (int mi = 0; mi < 4; ++mi)
#pragma unroll
      for (int ni = 0; ni < 4; ++ni) {
        acc[mi][ni] = __builtin_amdgcn_mfma_f32_16x16x32_bf16(ah[mi], bh[ni], acc[mi][ni], 0, 0, 0);
        acc[mi][ni] = __builtin_amdgcn_mfma_f32_16x16x32_bf16(al[mi], bh[ni], acc[mi][ni], 0, 0, 0);
        acc[mi][ni] = __builtin_amdgcn_mfma_f32_16x16x32_bf16(ah[mi], bl[ni], acc[mi][ni], 0, 0, 0);
      }
    __syncthreads();
  }
  // epilogue: C/D frag layout col=lane&15, row=(lane>>4)*4+j
#pragma unroll
  for (int mi = 0; mi < 4; ++mi)
#pragma unroll
    for (int ni = 0; ni < 4; ++ni)
#pragma unroll
      for (int j = 0; j < 4; ++j) {
        int m = m0 + wm*64 + mi*16 + (lane>>4)*4 + j;
        int n = n0 + wn*64 + ni*16 + (lane&15);
        float v = acc[mi][ni][j];
        if (EPI == 0) {
          C[(size_t)m*ldc + n] = v;
        } else if (EPI == 2) {
          v += bias[n];
          v = (v > 20.f) ? v : log1pf(__expf(v));
          C[(size_t)m*ldc + n] = v;
        } else if (EPI == 3) {
          C[(size_t)m*ldc + n] = v + res[(size_t)m*ldc + n];
        } else if (EPI == 4) {
          if (n < XPO_W) C[(size_t)m*XPO_W + n] = v;
          if (n < 64) {  // dlow split, zero-padded via dtw zeros (values here are finite)
            unsigned short hv = f2bf(v);
            oh[(size_t)m*64 + n] = hv;
            ol[(size_t)m*64 + n] = f2bf(v - bf2f(hv));
          }
        }
      }
}

// ---------------- causal depthwise conv (width 4) + SiLU, emits u hi/lo ----------------
__global__ __launch_bounds__(256) void conv_silu_kernel(
    const float* __restrict__ xz, const float* __restrict__ w,
    const float* __restrict__ cb,
    unsigned short* __restrict__ uh, unsigned short* __restrict__ ul) {
  int idx = blockIdx.x * 256 + threadIdx.x;
  if (idx >= NROWS * DIN) return;
  int d = idx % DIN;
  int r = idx / DIN;          // b*L + l
  int l = r & (LSEQ - 1);
  float acc = cb[d];
#pragma unroll
  for (int j = 0; j < 4; ++j) {
    int li = l - 3 + j;
    if (li >= 0)
      acc = fmaf(xz[(size_t)(r - l + li) * (2*DIN) + d], w[d*4 + j], acc);
  }
  float s = acc / (1.f + __expf(-acc));   // silu
  unsigned short hv = f2bf(s);
  uh[idx] = hv;
  ul[idx] = f2bf(s - bf2f(hv));
}

// ---------------- chunked selective scan ----------------
__global__ __launch_bounds__(256) void scan_pass1(
    const float* __restrict__ delta,
    const unsigned short* __restrict__ uh, const unsigned short* __restrict__ ul,
    const float* __restrict__ xpo, const float* __restrict__ A_log,
    float* __restrict__ carryA, float* __restrict__ carryH) {
  int d = blockIdx.x * 256 + threadIdx.x;
  int c = blockIdx.y, b = blockIdx.z;
  float A[16];
  {
    const float4* al = reinterpret_cast<const float4*>(A_log + (size_t)d * NST);
#pragma unroll
    for (int i = 0; i < 4; ++i) {
      float4 t = al[i];
      A[4*i+0] = -__expf(t.x); A[4*i+1] = -__expf(t.y);
      A[4*i+2] = -__expf(t.z); A[4*i+3] = -__expf(t.w);
    }
  }
  float h[16], ap[16];
#pragma unroll
  for (int n = 0; n < 16; ++n) { h[n] = 0.f; ap[n] = 1.f; }
  const float* dp = delta + ((size_t)b*LSEQ + c*CL) * DIN + d;
  const unsigned short* uhp = uh + ((size_t)b*LSEQ + c*CL) * DIN + d;
  const unsigned short* ulp = ul + ((size_t)b*LSEQ + c*CL) * DIN + d;
  const float* bp = xpo   + ((size_t)b*LSEQ + c*CL) * XPO_W + DTR;
  for (int l = 0; l < CL; ++l) {
    float dv = dp[(size_t)l*DIN];
    float uv = bf2f(uhp[(size_t)l*DIN]) + bf2f(ulp[(size_t)l*DIN]);
    float du = dv * uv;
    float Bv[16];
    {
      const float4* b4 = reinterpret_cast<const float4*>(bp + (size_t)l*XPO_W);
#pragma unroll
      for (int i = 0; i < 4; ++i) {
        float4 t = b4[i];
        Bv[4*i+0] = t.x; Bv[4*i+1] = t.y; Bv[4*i+2] = t.z; Bv[4*i+3] = t.w;
      }
    }
#pragma unroll
    for (int n = 0; n < 16; ++n) {
      float a = __expf(dv * A[n]);
      ap[n] *= a;
      h[n] = fmaf(a, h[n], du * Bv[n]);
    }
  }
  size_t ci = (((size_t)b*NC + c) * DIN + d) * NST;
  float4* ca = reinterpret_cast<float4*>(carryA + ci);
  float4* ch = reinterpret_cast<float4*>(carryH + ci);
#pragma unroll
  for (int i = 0; i < 4; ++i) {
    ca[i] = make_float4(ap[4*i], ap[4*i+1], ap[4*i+2], ap[4*i+3]);
    ch[i] = make_float4(h[4*i],  h[4*i+1],  h[4*i+2],  h[4*i+3]);
  }
}

__global__ __launch_bounds__(256) void scan_mid(
    const float* __restrict__ carryA, float* __restrict__ carryH) {
  int idx = blockIdx.x * 256 + threadIdx.x;
  int b = idx / (DIN*NST);
  int rem = idx - b * DIN*NST;
  float h = 0.f;
#pragma unroll
  for (int c = 0; c < NC; ++c) {
    size_t i = ((size_t)b*NC + c) * (DIN*NST) + rem;
    float a = carryA[i];
    float e = carryH[i];
    carryH[i] = h;
    h = fmaf(a, h, e);
  }
}

// pass2: recompute in-chunk scan seeded with h_in; y=(h·C+u·D)·silu(z), emit y hi/lo
__global__ __launch_bounds__(256) void scan_pass2(
    const float* __restrict__ delta,
    const unsigned short* __restrict__ uh, const unsigned short* __restrict__ ul,
    const float* __restrict__ xpo, const float* __restrict__ xz,
    const float* __restrict__ A_log, const float* __restrict__ Dp,
    const float* __restrict__ carryH,
    unsigned short* __restrict__ yh, unsigned short* __restrict__ yl) {
  int d = blockIdx.x * 256 + threadIdx.x;
  int c = blockIdx.y, b = blockIdx.z;
  float A[16];
  {
    const float4* al = reinterpret_cast<const float4*>(A_log + (size_t)d * NST);
#pragma unroll
    for (int i = 0; i < 4; ++i) {
      float4 t = al[i];
      A[4*i+0] = -__expf(t.x); A[4*i+1] = -__expf(t.y);
      A[4*i+2] = -__expf(t.z); A[4*i+3] = -__expf(t.w);
    }
  }
  float h[16];
  size_t ci = (((size_t)b*NC + c) * DIN + d) * NST;
  {
    const float4* ch = reinterpret_cast<const float4*>(carryH + ci);
#pragma unroll
    for (int i = 0; i < 4; ++i) {
      float4 t = ch[i];
      h[4*i+0] = t.x; h[4*i+1] = t.y; h[4*i+2] = t.z; h[4*i+3] = t.w;
    }
  }
  float Dd = Dp[d];
  const float* dp = delta + ((size_t)b*LSEQ + c*CL) * DIN + d;
  const unsigned short* uhp = uh + ((size_t)b*LSEQ + c*CL) * DIN + d;
  const unsigned short* ulp = ul + ((size_t)b*LSEQ + c*CL) * DIN + d;
  const float* bp = xpo   + ((size_t)b*LSEQ + c*CL) * XPO_W + DTR;
  const float* zp = xz    + ((size_t)b*LSEQ + c*CL) * (2*DIN) + DIN + d;
  size_t yi0 = ((size_t)b*LSEQ + c*CL) * DIN + d;
  for (int l = 0; l < CL; ++l) {
    float dv = dp[(size_t)l*DIN];
    float uv = bf2f(uhp[(size_t)l*DIN]) + bf2f(ulp[(size_t)l*DIN]);
    float du = dv * uv;
    float Bv[16], Cv[16];
    {
      const float4* b4 = reinterpret_cast<const float4*>(bp + (size_t)l*XPO_W);
#pragma unroll
      for (int i = 0; i < 4; ++i) {
        float4 t = b4[i];
        Bv[4*i+0] = t.x; Bv[4*i+1] = t.y; Bv[4*i+2] = t.z; Bv[4*i+3] = t.w;
        float4 tc = b4[i+4];
        Cv[4*i+0] = tc.x; Cv[4*i+1] = tc.y; Cv[4*i+2] = tc.z; Cv[4*i+3] = tc.w;
      }
    }
    float p = 0.f;
#pragma unroll
    for (int n = 0; n < 16; ++n) {
      float a = __expf(dv * A[n]);
      h[n] = fmaf(a, h[n], du * Bv[n]);
      p = fmaf(h[n], Cv[n], p);
    }
    float z = zp[(size_t)l*(2*DIN)];
    float sz = z / (1.f + __expf(-z));
    float yv = fmaf(uv, Dd, p) * sz;
    unsigned short hv = f2bf(yv);
    yh[yi0 + (size_t)l*DIN] = hv;
    yl[yi0 + (size_t)l*DIN] = f2bf(yv - bf2f(hv));
  }
}

extern "C" void kernel_launch(void* const* d_in, const int* in_sizes, int n_in,
                              void* d_out, int out_size, void* d_ws, size_t ws_size,
                              hipStream_t stream) {
  const float* x          = (const float*)d_in[0];
  const float* ln_g       = (const float*)d_in[1];
  const float* ln_b       = (const float*)d_in[2];
  const float* in_proj_w  = (const float*)d_in[3];   // (1536,384)
  const float* conv_w     = (const float*)d_in[4];   // (768,1,4)
  const float* conv_b     = (const float*)d_in[5];
  const float* x_proj_w   = (const float*)d_in[6];   // (80,768)
  const float* dt_proj_w  = (const float*)d_in[7];   // (768,48)
  const float* dt_proj_b  = (const float*)d_in[8];
  const float* A_log      = (const float*)d_in[9];   // (768,16)
  const float* D_param    = (const float*)d_in[10];
  const float* out_proj_w = (const float*)d_in[11];  // (384,768)

  char* w = (char*)d_ws;
  // region1 (12.58MB): xn hi/lo -> dlow hi/lo -> carryA/H (lifetimes disjoint)
  unsigned short* xn_h  = (unsigned short*)w;
  unsigned short* xn_l  = xn_h + (size_t)NROWS*DMODEL;
  unsigned short* dlow_h = (unsigned short*)w;
  unsigned short* dlow_l = dlow_h + (size_t)NROWS*64;
  float* carryA = (float*)w;
  float* carryH = carryA + (size_t)BSZ*NC*DIN*NST;
  char* p = w + (size_t)NROWS*DMODEL*4;               // 12,582,912
  float* xz = (float*)p;              p += (size_t)NROWS*2*DIN*4;   // 50.33MB
  unsigned short* u_h = (unsigned short*)p;
  unsigned short* u_l = u_h + (size_t)NROWS*DIN;      p += (size_t)NROWS*DIN*4; // 25.17MB
  float* xpo = (float*)p;             p += (size_t)NROWS*XPO_W*4;   // 2.62MB
  float* delta = (float*)p;           p += (size_t)NROWS*DIN*4;     // 25.17MB
  // weight splits for in_proj/x_proj live in the (not yet written) delta region
  unsigned short* inw_h = (unsigned short*)delta;
  unsigned short* inw_l = inw_h + (size_t)1536*384;
  unsigned short* xw_h  = inw_l + (size_t)1536*384;
  unsigned short* xw_l  = xw_h + (size_t)128*768;
  unsigned short* y2_h = (unsigned short*)p;
  unsigned short* y2_l = y2_h + (size_t)NROWS*DIN;    p += (size_t)NROWS*DIN*4; // 25.17MB
  unsigned short* dtw_h = (unsigned short*)p;
  unsigned short* dtw_l = dtw_h + (size_t)768*64;
  unsigned short* ow_h  = dtw_l + (size_t)768*64;
  unsigned short* ow_l  = ow_h + (size_t)384*768;

  // 0. split weights (pad x_proj_w rows 80->128, dt_proj_w cols 48->64)
  split_pad<<<(1536*384)/256, 256, 0, stream>>>(in_proj_w, 384, 1536, 384, inw_h, inw_l, 384);
  split_pad<<<(128*768)/256, 256, 0, stream>>>(x_proj_w, 768, 80, 768, xw_h, xw_l, 768);
  split_pad<<<(768*64)/256, 256, 0, stream>>>(dt_proj_w, 48, 768, 48, dtw_h, dtw_l, 64);
  split_pad<<<(384*768)/256, 256, 0, stream>>>(out_proj_w, 768, 384, 768, ow_h, ow_l, 768);

  // 1. LayerNorm -> xn hi/lo
  ln_kernel<<<NROWS, 64, 0, stream>>>(x, ln_g, ln_b, xn_h, xn_l);

  // 2. in_proj: xz = xn @ in_proj_w^T   (M=8192,N=1536,K=384)
  gemm_mfma<0><<<dim3(12, 64), 256, 0, stream>>>(xn_h, xn_l, DMODEL, inw_h, inw_l, DMODEL,
      xz, 2*DIN, nullptr, nullptr, nullptr, nullptr, DMODEL);

  // 3. conv + silu -> u hi/lo
  conv_silu_kernel<<<(NROWS*DIN)/256, 256, 0, stream>>>(xz, conv_w, conv_b, u_h, u_l);

  // 4. x_proj: xpo fp32 (n<80) + dlow hi/lo (n<64, K-padded)   (M=8192,Npad=128,K=768)
  gemm_mfma<4><<<dim3(1, 64), 256, 0, stream>>>(u_h, u_l, DIN, xw_h, xw_l, DIN,
      xpo, XPO_W, nullptr, nullptr, dlow_h, dlow_l, DIN);

  // 5. dt_proj + bias + softplus -> delta   (M=8192,N=768,Kpad=64)
  gemm_mfma<2><<<dim3(6, 64), 256, 0, stream>>>(dlow_h, dlow_l, 64, dtw_h, dtw_l, 64,
      delta, DIN, dt_proj_b, nullptr, nullptr, nullptr, 64);

  // 6. chunked selective scan -> y2 hi/lo
  {
    dim3 g1(DIN/256, NC, BSZ);
    scan_pass1<<<g1, 256, 0, stream>>>(delta, u_h, u_l, xpo, A_log, carryA, carryH);
    scan_mid<<<(BSZ*DIN*NST)/256, 256, 0, stream>>>(carryA, carryH);
    scan_pass2<<<g1, 256, 0, stream>>>(delta, u_h, u_l, xpo, xz, A_log, D_param,
                                       carryH, y2_h, y2_l);
  }

  // 7. out_proj + residual -> d_out   (M=8192,N=384,K=768)
  gemm_mfma<3><<<dim3(3, 64), 256, 0, stream>>>(y2_h, y2_l, DIN, ow_h, ow_l, DIN,
      (float*)d_out, DMODEL, nullptr, x, nullptr, nullptr, DIN);
}

// Round 4
// 285.500 us; speedup vs baseline: 4.4098x; 1.0843x over previous
//
#include <hip/hip_runtime.h>
#include <math.h>

#define DMODEL 384
#define DIN 768
#define NST 16
#define DTR 48
#define BSZ 8
#define LSEQ 1024
#define NROWS (BSZ*LSEQ)      // 8192
#define XPO_W (DTR + 2*NST)   // 80
#define CL 64                 // chunk length for scan
#define NC (LSEQ/CL)          // 16 chunks

typedef __attribute__((ext_vector_type(8))) short bf16x8;
typedef __attribute__((ext_vector_type(4))) float f32x4;

__device__ __forceinline__ unsigned short f2bf(float x) {
  unsigned int u = __float_as_uint(x);
  unsigned int r = u + 0x7fffu + ((u >> 16) & 1u);
  return (unsigned short)(r >> 16);
}
__device__ __forceinline__ float bf2f(unsigned short h) {
  return __uint_as_float(((unsigned int)h) << 16);
}

__device__ __forceinline__ void gll16(const void* g, void* l) {
  __builtin_amdgcn_global_load_lds(
      (const __attribute__((address_space(1))) void*)g,
      (__attribute__((address_space(3))) void*)l, 16, 0, 0);
}

// ---------------- LayerNorm: 4 rows per 256-thread block, emits hi/lo bf16 ----------------
__global__ __launch_bounds__(256) void ln_kernel(const float* __restrict__ x,
    const float* __restrict__ g, const float* __restrict__ b,
    unsigned short* __restrict__ xh, unsigned short* __restrict__ xl) {
  int row = blockIdx.x * 4 + (threadIdx.x >> 6);
  int lane = threadIdx.x & 63;
  const float* xr = x + (size_t)row * DMODEL;
  float v[6];
  float s = 0.f, ss = 0.f;
#pragma unroll
  for (int i = 0; i < 6; ++i) { v[i] = xr[lane + i*64]; s += v[i]; ss += v[i]*v[i]; }
#pragma unroll
  for (int off = 32; off; off >>= 1) { s += __shfl_xor(s, off); ss += __shfl_xor(ss, off); }
  float mu = s * (1.f / DMODEL);
  float var = ss * (1.f / DMODEL) - mu * mu;
  float inv = rsqrtf(var + 1e-5f);
#pragma unroll
  for (int i = 0; i < 6; ++i) {
    int c = lane + i*64;
    float o = (v[i] - mu) * inv * g[c] + b[c];
    unsigned short hv = f2bf(o);
    xh[(size_t)row*DMODEL + c] = hv;
    xl[(size_t)row*DMODEL + c] = f2bf(o - bf2f(hv));
  }
}

// ---------------- single fused weight split+pad kernel ----------------
__device__ __forceinline__ void split_one(const float* src, int ldsrc, int R, int C,
    unsigned short* dh, unsigned short* dl, int Cpad, int i) {
  int r = i / Cpad, c = i - r * Cpad;
  float v = (r < R && c < C) ? src[(size_t)r*ldsrc + c] : 0.f;
  unsigned short hv = f2bf(v);
  dh[i] = hv;
  dl[i] = f2bf(v - bf2f(hv));
}
#define N_INW (1536*384)
#define N_XW  (128*768)
#define N_DTW (768*64)
#define N_OW  (384*768)
__global__ __launch_bounds__(256) void split_weights(
    const float* __restrict__ inw, const float* __restrict__ xw,
    const float* __restrict__ dtw, const float* __restrict__ ow,
    unsigned short* inw_h, unsigned short* inw_l,
    unsigned short* xw_h, unsigned short* xw_l,
    unsigned short* dtw_h, unsigned short* dtw_l,
    unsigned short* ow_h, unsigned short* ow_l) {
  int i = blockIdx.x * 256 + threadIdx.x;
  if (i < N_INW) { split_one(inw, 384, 1536, 384, inw_h, inw_l, 384, i); return; }
  i -= N_INW;
  if (i < N_XW)  { split_one(xw, 768, 80, 768, xw_h, xw_l, 768, i); return; }
  i -= N_XW;
  if (i < N_DTW) { split_one(dtw, 48, 768, 48, dtw_h, dtw_l, 64, i); return; }
  i -= N_DTW;
  if (i < N_OW)  { split_one(ow, 768, 384, 768, ow_h, ow_l, 768, i); return; }
}

// ---------------- MFMA split-bf16 GEMM, 2-phase double-buffered ----------------
// C[M,Npad] = A[M,K] * B[Npad,K]^T. 128x128 tile, BK=32, 4 waves (2x2), 16x16x32 bf16.
// EPI: 0 plain, 2 bias+softplus, 3 residual add, 4 x_proj (xpo fp32 + dlow hi/lo)
template<int EPI>
__global__ __launch_bounds__(256, 2) void gemm_mfma(
    const unsigned short* __restrict__ Ah, const unsigned short* __restrict__ Al, int lda,
    const unsigned short* __restrict__ Bh, const unsigned short* __restrict__ Bl, int ldb,
    float* __restrict__ C, int ldc,
    const float* __restrict__ bias, const float* __restrict__ res,
    unsigned short* __restrict__ oh, unsigned short* __restrict__ ol,
    int K) {
  // [buf][arr: Ah,Al,Bh,Bl][cell(512) x 8 bf16] = 64 KB
  __shared__ unsigned short lds[2][4][4096];
  int tid = threadIdx.x;
  int lane = tid & 63, wid = tid >> 6;
  int wm = wid >> 1, wn = wid & 1;

  // bijective XCD swizzle (all grids have nwg % 8 == 0)
  unsigned nwg = gridDim.x * gridDim.y;
  unsigned bid = blockIdx.y * gridDim.x + blockIdx.x;
  unsigned cpx = nwg >> 3;
  unsigned sw = (bid & 7) * cpx + (bid >> 3);
  unsigned bx = sw % gridDim.x, by = sw / gridDim.x;
  int m0 = by * 128, n0 = bx * 128;

  f32x4 acc[4][4];
#pragma unroll
  for (int i = 0; i < 4; ++i)
#pragma unroll
    for (int j = 0; j < 4; ++j) acc[i][j] = (f32x4){0.f, 0.f, 0.f, 0.f};

  int kgl = lane >> 4, rl = lane & 15;

  // per-wave staging geometry: wave fills cells [wid*128, wid*128+128)
  int c0 = wid*128 + lane;        // j=0 cell
  int c1 = wid*128 + 64 + lane;   // j=1 cell
  int r0 = c0 & 127, kg0 = c0 >> 7;
  int r1 = c1 & 127, kg1 = c1 >> 7;

#define STAGE(bf, kt) do { \
    size_t ga0 = (size_t)(m0 + r0) * lda + (kt) + kg0*8; \
    size_t gb0 = (size_t)(n0 + r0) * ldb + (kt) + kg0*8; \
    size_t ga1 = (size_t)(m0 + r1) * lda + (kt) + kg1*8; \
    size_t gb1 = (size_t)(n0 + r1) * ldb + (kt) + kg1*8; \
    gll16(Ah + ga0, &lds[bf][0][(wid*128)*8]); \
    gll16(Al + ga0, &lds[bf][1][(wid*128)*8]); \
    gll16(Bh + gb0, &lds[bf][2][(wid*128)*8]); \
    gll16(Bl + gb0, &lds[bf][3][(wid*128)*8]); \
    gll16(Ah + ga1, &lds[bf][0][(wid*128+64)*8]); \
    gll16(Al + ga1, &lds[bf][1][(wid*128+64)*8]); \
    gll16(Bh + gb1, &lds[bf][2][(wid*128+64)*8]); \
    gll16(Bl + gb1, &lds[bf][3][(wid*128+64)*8]); \
  } while (0)

  int T = K >> 5;
  STAGE(0, 0);
  asm volatile("s_waitcnt vmcnt(0)" ::: "memory");
  __builtin_amdgcn_s_barrier();

  int cur = 0;
  for (int t = 0; t < T; ++t) {
    if (t + 1 < T) {
      STAGE(cur ^ 1, (t + 1) << 5);
    }
    asm volatile("" ::: "memory");
    bf16x8 ah[4], al[4], bh[4], bl[4];
#pragma unroll
    for (int mi = 0; mi < 4; ++mi) {
      int cell = kgl*128 + wm*64 + mi*16 + rl;
      ah[mi] = *reinterpret_cast<const bf16x8*>(&lds[cur][0][cell*8]);
      al[mi] = *reinterpret_cast<const bf16x8*>(&lds[cur][1][cell*8]);
    }
#pragma unroll
    for (int ni = 0; ni < 4; ++ni) {
      int cell = kgl*128 + wn*64 + ni*16 + rl;
      bh[ni] = *reinterpret_cast<const bf16x8*>(&lds[cur][2][cell*8]);
      bl[ni] = *reinterpret_cast<const bf16x8*>(&lds[cur][3][cell*8]);
    }
#pragma unroll
    for (int mi = 0; mi < 4; ++mi)
#pragma unroll
      for (int ni = 0; ni < 4; ++ni) {
        acc[mi][ni] = __builtin_amdgcn_mfma_f32_16x16x32_bf16(ah[mi], bh[ni], acc[mi][ni], 0, 0, 0);
        acc[mi][ni] = __builtin_amdgcn_mfma_f32_16x16x32_bf16(al[mi], bh[ni], acc[mi][ni], 0, 0, 0);
        acc[mi][ni] = __builtin_amdgcn_mfma_f32_16x16x32_bf16(ah[mi], bl[ni], acc[mi][ni], 0, 0, 0);
      }
    asm volatile("s_waitcnt vmcnt(0)" ::: "memory");
    __builtin_amdgcn_s_barrier();
    cur ^= 1;
  }
#undef STAGE

  // epilogue: C/D frag layout col=lane&15, row=(lane>>4)*4+j
#pragma unroll
  for (int mi = 0; mi < 4; ++mi)
#pragma unroll
    for (int ni = 0; ni < 4; ++ni)
#pragma unroll
      for (int j = 0; j < 4; ++j) {
        int m = m0 + wm*64 + mi*16 + (lane>>4)*4 + j;
        int n = n0 + wn*64 + ni*16 + (lane&15);
        float v = acc[mi][ni][j];
        if (EPI == 0) {
          C[(size_t)m*ldc + n] = v;
        } else if (EPI == 2) {
          v += bias[n];
          v = (v > 20.f) ? v : log1pf(__expf(v));
          C[(size_t)m*ldc + n] = v;
        } else if (EPI == 3) {
          C[(size_t)m*ldc + n] = v + res[(size_t)m*ldc + n];
        } else if (EPI == 4) {
          if (n < XPO_W) C[(size_t)m*XPO_W + n] = v;
          if (n < 64) {
            unsigned short hv = f2bf(v);
            oh[(size_t)m*64 + n] = hv;
            ol[(size_t)m*64 + n] = f2bf(v - bf2f(hv));
          }
        }
      }
}

// ---------------- causal depthwise conv (width 4) + SiLU, emits u hi/lo ----------------
__global__ __launch_bounds__(256) void conv_silu_kernel(
    const float* __restrict__ xz, const float* __restrict__ w,
    const float* __restrict__ cb,
    unsigned short* __restrict__ uh, unsigned short* __restrict__ ul) {
  int r = blockIdx.x / 3;                       // row (b*L + l)
  int d = (blockIdx.x % 3) * 256 + threadIdx.x; // channel
  int l = r & (LSEQ - 1);
  size_t idx = (size_t)r * DIN + d;
  float acc = cb[d];
#pragma unroll
  for (int j = 0; j < 4; ++j) {
    int li = l - 3 + j;
    if (li >= 0)
      acc = fmaf(xz[(size_t)(r - l + li) * (2*DIN) + d], w[d*4 + j], acc);
  }
  float s = acc / (1.f + __expf(-acc));   // silu
  unsigned short hv = f2bf(s);
  uh[idx] = hv;
  ul[idx] = f2bf(s - bf2f(hv));
}

// ---------------- chunked selective scan ----------------
__global__ __launch_bounds__(256) void scan_pass1(
    const float* __restrict__ delta,
    const unsigned short* __restrict__ uh, const unsigned short* __restrict__ ul,
    const float* __restrict__ xpo, const float* __restrict__ A_log,
    float* __restrict__ carryA, float* __restrict__ carryH) {
  int d = blockIdx.x * 256 + threadIdx.x;
  int c = blockIdx.y, b = blockIdx.z;
  float A[16];
  {
    const float4* al = reinterpret_cast<const float4*>(A_log + (size_t)d * NST);
#pragma unroll
    for (int i = 0; i < 4; ++i) {
      float4 t = al[i];
      A[4*i+0] = -__expf(t.x); A[4*i+1] = -__expf(t.y);
      A[4*i+2] = -__expf(t.z); A[4*i+3] = -__expf(t.w);
    }
  }
  float h[16], ap[16];
#pragma unroll
  for (int n = 0; n < 16; ++n) { h[n] = 0.f; ap[n] = 1.f; }
  const float* dp = delta + ((size_t)b*LSEQ + c*CL) * DIN + d;
  const unsigned short* uhp = uh + ((size_t)b*LSEQ + c*CL) * DIN + d;
  const unsigned short* ulp = ul + ((size_t)b*LSEQ + c*CL) * DIN + d;
  const float* bp = xpo   + ((size_t)b*LSEQ + c*CL) * XPO_W + DTR;
  for (int l = 0; l < CL; ++l) {
    float dv = dp[(size_t)l*DIN];
    float uv = bf2f(uhp[(size_t)l*DIN]) + bf2f(ulp[(size_t)l*DIN]);
    float du = dv * uv;
    float Bv[16];
    {
      const float4* b4 = reinterpret_cast<const float4*>(bp + (size_t)l*XPO_W);
#pragma unroll
      for (int i = 0; i < 4; ++i) {
        float4 t = b4[i];
        Bv[4*i+0] = t.x; Bv[4*i+1] = t.y; Bv[4*i+2] = t.z; Bv[4*i+3] = t.w;
      }
    }
#pragma unroll
    for (int n = 0; n < 16; ++n) {
      float a = __expf(dv * A[n]);
      ap[n] *= a;
      h[n] = fmaf(a, h[n], du * Bv[n]);
    }
  }
  size_t ci = (((size_t)b*NC + c) * DIN + d) * NST;
  float4* ca = reinterpret_cast<float4*>(carryA + ci);
  float4* ch = reinterpret_cast<float4*>(carryH + ci);
#pragma unroll
  for (int i = 0; i < 4; ++i) {
    ca[i] = make_float4(ap[4*i], ap[4*i+1], ap[4*i+2], ap[4*i+3]);
    ch[i] = make_float4(h[4*i],  h[4*i+1],  h[4*i+2],  h[4*i+3]);
  }
}

__global__ __launch_bounds__(256) void scan_mid(
    const float* __restrict__ carryA, float* __restrict__ carryH) {
  int idx = blockIdx.x * 256 + threadIdx.x;
  int b = idx / (DIN*NST);
  int rem = idx - b * DIN*NST;
  float h = 0.f;
#pragma unroll
  for (int c = 0; c < NC; ++c) {
    size_t i = ((size_t)b*NC + c) * (DIN*NST) + rem;
    float a = carryA[i];
    float e = carryH[i];
    carryH[i] = h;
    h = fmaf(a, h, e);
  }
}

// pass2: recompute in-chunk scan seeded with h_in; y=(h·C+u·D)·silu(z), emit y hi/lo
__global__ __launch_bounds__(256) void scan_pass2(
    const float* __restrict__ delta,
    const unsigned short* __restrict__ uh, const unsigned short* __restrict__ ul,
    const float* __restrict__ xpo, const float* __restrict__ xz,
    const float* __restrict__ A_log, const float* __restrict__ Dp,
    const float* __restrict__ carryH,
    unsigned short* __restrict__ yh, unsigned short* __restrict__ yl) {
  int d = blockIdx.x * 256 + threadIdx.x;
  int c = blockIdx.y, b = blockIdx.z;
  float A[16];
  {
    const float4* al = reinterpret_cast<const float4*>(A_log + (size_t)d * NST);
#pragma unroll
    for (int i = 0; i < 4; ++i) {
      float4 t = al[i];
      A[4*i+0] = -__expf(t.x); A[4*i+1] = -__expf(t.y);
      A[4*i+2] = -__expf(t.z); A[4*i+3] = -__expf(t.w);
    }
  }
  float h[16];
  size_t ci = (((size_t)b*NC + c) * DIN + d) * NST;
  {
    const float4* ch = reinterpret_cast<const float4*>(carryH + ci);
#pragma unroll
    for (int i = 0; i < 4; ++i) {
      float4 t = ch[i];
      h[4*i+0] = t.x; h[4*i+1] = t.y; h[4*i+2] = t.z; h[4*i+3] = t.w;
    }
  }
  float Dd = Dp[d];
  const float* dp = delta + ((size_t)b*LSEQ + c*CL) * DIN + d;
  const unsigned short* uhp = uh + ((size_t)b*LSEQ + c*CL) * DIN + d;
  const unsigned short* ulp = ul + ((size_t)b*LSEQ + c*CL) * DIN + d;
  const float* bp = xpo   + ((size_t)b*LSEQ + c*CL) * XPO_W + DTR;
  const float* zp = xz    + ((size_t)b*LSEQ + c*CL) * (2*DIN) + DIN + d;
  size_t yi0 = ((size_t)b*LSEQ + c*CL) * DIN + d;
  for (int l = 0; l < CL; ++l) {
    float dv = dp[(size_t)l*DIN];
    float uv = bf2f(uhp[(size_t)l*DIN]) + bf2f(ulp[(size_t)l*DIN]);
    float du = dv * uv;
    float Bv[16], Cv[16];
    {
      const float4* b4 = reinterpret_cast<const float4*>(bp + (size_t)l*XPO_W);
#pragma unroll
      for (int i = 0; i < 4; ++i) {
        float4 t = b4[i];
        Bv[4*i+0] = t.x; Bv[4*i+1] = t.y; Bv[4*i+2] = t.z; Bv[4*i+3] = t.w;
        float4 tc = b4[i+4];
        Cv[4*i+0] = tc.x; Cv[4*i+1] = tc.y; Cv[4*i+2] = tc.z; Cv[4*i+3] = tc.w;
      }
    }
    float p = 0.f;
#pragma unroll
    for (int n = 0; n < 16; ++n) {
      float a = __expf(dv * A[n]);
      h[n] = fmaf(a, h[n], du * Bv[n]);
      p = fmaf(h[n], Cv[n], p);
    }
    float z = zp[(size_t)l*(2*DIN)];
    float sz = z / (1.f + __expf(-z));
    float yv = fmaf(uv, Dd, p) * sz;
    unsigned short hv = f2bf(yv);
    yh[yi0 + (size_t)l*DIN] = hv;
    yl[yi0 + (size_t)l*DIN] = f2bf(yv - bf2f(hv));
  }
}

extern "C" void kernel_launch(void* const* d_in, const int* in_sizes, int n_in,
                              void* d_out, int out_size, void* d_ws, size_t ws_size,
                              hipStream_t stream) {
  const float* x          = (const float*)d_in[0];
  const float* ln_g       = (const float*)d_in[1];
  const float* ln_b       = (const float*)d_in[2];
  const float* in_proj_w  = (const float*)d_in[3];   // (1536,384)
  const float* conv_w     = (const float*)d_in[4];   // (768,1,4)
  const float* conv_b     = (const float*)d_in[5];
  const float* x_proj_w   = (const float*)d_in[6];   // (80,768)
  const float* dt_proj_w  = (const float*)d_in[7];   // (768,48)
  const float* dt_proj_b  = (const float*)d_in[8];
  const float* A_log      = (const float*)d_in[9];   // (768,16)
  const float* D_param    = (const float*)d_in[10];
  const float* out_proj_w = (const float*)d_in[11];  // (384,768)

  char* w = (char*)d_ws;
  // region1 (12.58MB): xn hi/lo -> dlow hi/lo -> carryA/H (lifetimes disjoint)
  unsigned short* xn_h  = (unsigned short*)w;
  unsigned short* xn_l  = xn_h + (size_t)NROWS*DMODEL;
  unsigned short* dlow_h = (unsigned short*)w;
  unsigned short* dlow_l = dlow_h + (size_t)NROWS*64;
  float* carryA = (float*)w;
  float* carryH = carryA + (size_t)BSZ*NC*DIN*NST;
  char* p = w + (size_t)NROWS*DMODEL*4;               // 12,582,912
  float* xz = (float*)p;              p += (size_t)NROWS*2*DIN*4;   // 50.33MB
  unsigned short* u_h = (unsigned short*)p;
  unsigned short* u_l = u_h + (size_t)NROWS*DIN;      p += (size_t)NROWS*DIN*4; // 25.17MB
  float* xpo = (float*)p;             p += (size_t)NROWS*XPO_W*4;   // 2.62MB
  float* delta = (float*)p;           p += (size_t)NROWS*DIN*4;     // 25.17MB
  // weight splits for in_proj/x_proj live in the (not yet written) delta region
  unsigned short* inw_h = (unsigned short*)delta;
  unsigned short* inw_l = inw_h + (size_t)1536*384;
  unsigned short* xw_h  = inw_l + (size_t)1536*384;
  unsigned short* xw_l  = xw_h + (size_t)128*768;
  unsigned short* y2_h = (unsigned short*)p;
  unsigned short* y2_l = y2_h + (size_t)NROWS*DIN;    p += (size_t)NROWS*DIN*4; // 25.17MB
  unsigned short* dtw_h = (unsigned short*)p;
  unsigned short* dtw_l = dtw_h + (size_t)768*64;
  unsigned short* ow_h  = dtw_l + (size_t)768*64;
  unsigned short* ow_l  = ow_h + (size_t)384*768;

  // 0. split all weights in one launch (pads: x_proj rows 80->128, dt_proj cols 48->64)
  split_weights<<<(N_INW+N_XW+N_DTW+N_OW)/256, 256, 0, stream>>>(
      in_proj_w, x_proj_w, dt_proj_w, out_proj_w,
      inw_h, inw_l, xw_h, xw_l, dtw_h, dtw_l, ow_h, ow_l);

  // 1. LayerNorm -> xn hi/lo
  ln_kernel<<<NROWS/4, 256, 0, stream>>>(x, ln_g, ln_b, xn_h, xn_l);

  // 2. in_proj: xz = xn @ in_proj_w^T   (M=8192,N=1536,K=384)
  gemm_mfma<0><<<dim3(12, 64), 256, 0, stream>>>(xn_h, xn_l, DMODEL, inw_h, inw_l, DMODEL,
      xz, 2*DIN, nullptr, nullptr, nullptr, nullptr, DMODEL);

  // 3. conv + silu -> u hi/lo
  conv_silu_kernel<<<NROWS*3, 256, 0, stream>>>(xz, conv_w, conv_b, u_h, u_l);

  // 4. x_proj: xpo fp32 (n<80) + dlow hi/lo (n<64, K-padded)   (M=8192,Npad=128,K=768)
  gemm_mfma<4><<<dim3(1, 64), 256, 0, stream>>>(u_h, u_l, DIN, xw_h, xw_l, DIN,
      xpo, XPO_W, nullptr, nullptr, dlow_h, dlow_l, DIN);

  // 5. dt_proj + bias + softplus -> delta   (M=8192,N=768,Kpad=64)
  gemm_mfma<2><<<dim3(6, 64), 256, 0, stream>>>(dlow_h, dlow_l, 64, dtw_h, dtw_l, 64,
      delta, DIN, dt_proj_b, nullptr, nullptr, nullptr, 64);

  // 6. chunked selective scan -> y2 hi/lo
  {
    dim3 g1(DIN/256, NC, BSZ);
    scan_pass1<<<g1, 256, 0, stream>>>(delta, u_h, u_l, xpo, A_log, carryA, carryH);
    scan_mid<<<(BSZ*DIN*NST)/256, 256, 0, stream>>>(carryA, carryH);
    scan_pass2<<<g1, 256, 0, stream>>>(delta, u_h, u_l, xpo, xz, A_log, D_param,
                                       carryH, y2_h, y2_l);
  }

  // 7. out_proj + residual -> d_out   (M=8192,N=384,K=768)
  gemm_mfma<3><<<dim3(3, 64), 256, 0, stream>>>(y2_h, y2_l, DIN, ow_h, ow_l, DIN,
      (float*)d_out, DMODEL, nullptr, x, nullptr, nullptr, DIN);
}